// Round 1
// 1273.167 us; speedup vs baseline: 1.0902x; 1.0902x over previous
//
#include <hip/hip_runtime.h>

// EquiConv fully-fused pipeline (round 2).
// E = 200000, MUL_S = 128, MUL_V = 64, FC_IN = 128, FC_HID = 64, LEN_W = 192.
//
// Design: lane = edge (64 lanes/wave = 64 edges/block), wave = column slice.
// Block = 512 threads = 8 waves; wave `wid` owns scal cols [wid*16, wid*16+16)
// and w-indices [wid*8, wid*8+8). Weights are read through SGPRs (wave-uniform
// addresses via readfirstlane), activations are lane-private register chunks.
// Only h0/h1 go through LDS (2 barriers/block). Each lane computes and stores
// its own outputs entirely in registers -> no S1/wfc HBM round trips.
//
// ws layout (floats):
//   [0)        Wbig  128x256  = [w1_p0|w1_p1|w1_p2] cols pre-scaled by w2_*, INV_S, SQ2
//   [32768)    Wd    64x192   = [w1_p4|w1_p5] cols pre-scaled by w2_*, INV_V, SQ3, SQ2
//   [45056)    Wp3   64x64    = w1_p3 cols pre-scaled by w2_p3, INV_V, SQ2

__device__ __forceinline__ float sigmoidf_(float x) { return 1.0f / (1.0f + __expf(-x)); }

// ---------------------------------------------------------------- prep
__global__ __launch_bounds__(256) void prep_weights(
    const float* __restrict__ w1_p0, const float* __restrict__ w2_p0,
    const float* __restrict__ w1_p1, const float* __restrict__ w2_p1,
    const float* __restrict__ w1_p2, const float* __restrict__ w2_p2,
    const float* __restrict__ w1_p3, const float* __restrict__ w2_p3,
    const float* __restrict__ w1_p4, const float* __restrict__ w2_p4,
    const float* __restrict__ w1_p5, const float* __restrict__ w2_p5,
    float* __restrict__ Wbig, float* __restrict__ Wd, float* __restrict__ Wp3)
{
    const float INV_S = 0.08838834764831845f;   // 1/sqrt(128)
    const float INV_V = 0.125f;                 // 1/sqrt(64)
    const float SQ2   = 0.7071067811865476f;
    const float SQ3   = 0.5773502691896258f;
    int gid = blockIdx.x * 256 + threadIdx.x;
    if (gid < 128*256) {
        int k = gid >> 8, c = gid & 255;
        float v;
        if (c < 128)      v = w1_p0[k*128 + c]       * w2_p0[c]       * (INV_S*SQ2);
        else if (c < 192) v = w1_p1[k*64 + (c-128)]  * w2_p1[c-128]   * (INV_S*SQ2);
        else              v = w1_p2[k*64 + (c-192)]  * w2_p2[c-192]   * (INV_S*SQ2);
        Wbig[gid] = v;
    } else if (gid < 128*256 + 64*192) {
        int g = gid - 128*256;
        int u = g / 192, c = g - u*192;
        float v;
        if (c < 128) v = w1_p4[u*128 + c]        * w2_p4[c]     * (INV_V*SQ3*SQ2);
        else         v = w1_p5[u*64 + (c-128)]   * w2_p5[c-128] * (INV_V*SQ3*SQ2);
        Wd[g] = v;
    } else if (gid < 128*256 + 64*192 + 64*64) {
        int g = gid - (128*256 + 64*192);
        int w = g & 63;
        Wp3[g] = w1_p3[g] * w2_p3[w] * (INV_V*SQ2);
    }
}

// ---------------------------------------------------------------- fused
__global__ __launch_bounds__(512, 2) void fused_kernel(
    const float* __restrict__ fea_in1, const float* __restrict__ fea_in2,
    const float* __restrict__ fea_w,
    const float* __restrict__ fc_w0, const float* __restrict__ fc_b0,
    const float* __restrict__ fc_w1, const float* __restrict__ fc_b1,
    const float* __restrict__ fc_w2, const float* __restrict__ fc_b2,
    const float* __restrict__ Wbig, const float* __restrict__ Wd,
    const float* __restrict__ Wp3,
    float* __restrict__ out)
{
    __shared__ float h0T[4096];   // [col][edge] 64x64
    __shared__ float h1T[4096];   // [col][edge] 64x64

    const int t   = threadIdx.x;
    const int l   = t & 63;                                  // lane = edge-in-block
    const int wid = __builtin_amdgcn_readfirstlane(t >> 6);  // uniform wave id 0..7
    const int sc0 = wid * 16;    // this wave's scal-column base (0..112)
    const int wv0 = wid * 8;     // this wave's w-index base     (0..56)
    const long e  = (long)blockIdx.x * 64 + l;

    const float* rw = fea_w   + e * 128;   // lane-private fea_weight row
    const float* rx = fea_in1 + e * 320;   // lane-private fea_in1 row

    // ---------------- FC layer 0: h0 = silu(fw @ w0 + b0); wave's 8 cols, K=128
    float ha[8];
    #pragma unroll
    for (int j = 0; j < 8; ++j) ha[j] = fc_b0[wv0 + j];
    #pragma unroll 2
    for (int kc = 0; kc < 32; ++kc) {
        float4 x4 = *(const float4*)(rw + kc * 4);
        float xs[4] = {x4.x, x4.y, x4.z, x4.w};
        #pragma unroll
        for (int kk = 0; kk < 4; ++kk) {
            const float* wr = fc_w0 + (kc * 4 + kk) * 64 + wv0;   // uniform -> s_load
            #pragma unroll
            for (int j = 0; j < 8; ++j) ha[j] = fmaf(xs[kk], wr[j], ha[j]);
        }
    }
    #pragma unroll
    for (int j = 0; j < 8; ++j) {
        float z = ha[j];
        h0T[(wv0 + j) * 64 + l] = z * sigmoidf_(z);
    }
    __syncthreads();

    // ---------------- FC layer 1: h1 = silu(h0 @ w1 + b1); 8 cols, K=64
    #pragma unroll
    for (int j = 0; j < 8; ++j) ha[j] = fc_b1[wv0 + j];
    #pragma unroll 4
    for (int k = 0; k < 64; ++k) {
        float x = h0T[k * 64 + l];
        const float* wr = fc_w1 + k * 64 + wv0;
        #pragma unroll
        for (int j = 0; j < 8; ++j) ha[j] = fmaf(x, wr[j], ha[j]);
    }
    #pragma unroll
    for (int j = 0; j < 8; ++j) {
        float z = ha[j];
        h1T[(wv0 + j) * 64 + l] = z * sigmoidf_(z);
    }
    __syncthreads();

    // ---------------- FC layer 2: W = h1 @ w2 + b2; 16 scal + 8 gate cols, K=64
    float aWs[16], aWg[8];
    #pragma unroll
    for (int j = 0; j < 16; ++j) aWs[j] = fc_b2[sc0 + j];
    #pragma unroll
    for (int j = 0; j < 8; ++j)  aWg[j] = fc_b2[128 + wv0 + j];
    #pragma unroll 2
    for (int k = 0; k < 64; ++k) {
        float x = h1T[k * 64 + l];
        const float* wr = fc_w2 + k * 192;
        #pragma unroll
        for (int j = 0; j < 16; ++j) aWs[j] = fmaf(x, wr[sc0 + j], aWs[j]);
        #pragma unroll
        for (int j = 0; j < 8; ++j)  aWg[j] = fmaf(x, wr[128 + wv0 + j], aWg[j]);
    }

    // ---------------- S1 = x1s @ Wbig; 16 scal + 8 gate + 8 vcoef cols, K=128
    float aS1s[16], aS1g[8], aS1v[8];
    #pragma unroll
    for (int j = 0; j < 16; ++j) aS1s[j] = 0.f;
    #pragma unroll
    for (int j = 0; j < 8; ++j) { aS1g[j] = 0.f; aS1v[j] = 0.f; }
    #pragma unroll 2
    for (int kc = 0; kc < 32; ++kc) {
        float4 x4 = *(const float4*)(rx + kc * 4);
        float xs[4] = {x4.x, x4.y, x4.z, x4.w};
        #pragma unroll
        for (int kk = 0; kk < 4; ++kk) {
            const float* wr = Wbig + (kc * 4 + kk) * 256;
            #pragma unroll
            for (int j = 0; j < 16; ++j) aS1s[j] = fmaf(xs[kk], wr[sc0 + j], aS1s[j]);
            #pragma unroll
            for (int j = 0; j < 8; ++j)  aS1g[j] = fmaf(xs[kk], wr[128 + wv0 + j], aS1g[j]);
            #pragma unroll
            for (int j = 0; j < 8; ++j)  aS1v[j] = fmaf(xs[kk], wr[192 + wv0 + j], aS1v[j]);
        }
    }

    // ---------------- vector branch: A3 (8w x 3i), d, S2 (16 scal + 8 gate), K=64 over u
    float4 x2r = *(const float4*)(fea_in2 + e * 4);   // x2s = .x, x2v = .y/.z/.w
    float aS2s[16], aS2g[8], aA3[8][3];
    #pragma unroll
    for (int j = 0; j < 16; ++j) aS2s[j] = 0.f;
    #pragma unroll
    for (int j = 0; j < 8; ++j) {
        aS2g[j] = 0.f;
        aA3[j][0] = 0.f; aA3[j][1] = 0.f; aA3[j][2] = 0.f;
    }
    const float* rv = rx + 128;   // lane-private x1v row (64 u x 3 i)
    for (int uc = 0; uc < 16; ++uc) {
        float4 a = *(const float4*)(rv + uc * 12);
        float4 b = *(const float4*)(rv + uc * 12 + 4);
        float4 c = *(const float4*)(rv + uc * 12 + 8);
        float xv[12] = {a.x,a.y,a.z,a.w, b.x,b.y,b.z,b.w, c.x,c.y,c.z,c.w};
        #pragma unroll
        for (int uu = 0; uu < 4; ++uu) {
            const int u = uc * 4 + uu;
            const float v0 = xv[uu*3+0], v1 = xv[uu*3+1], v2 = xv[uu*3+2];
            const float* wp = Wp3 + u * 64 + wv0;
            #pragma unroll
            for (int j = 0; j < 8; ++j) {
                const float w = wp[j];
                aA3[j][0] = fmaf(v0, w, aA3[j][0]);
                aA3[j][1] = fmaf(v1, w, aA3[j][1]);
                aA3[j][2] = fmaf(v2, w, aA3[j][2]);
            }
            const float du = v0 * x2r.y + v1 * x2r.z + v2 * x2r.w;
            const float* wd = Wd + u * 192;
            #pragma unroll
            for (int j = 0; j < 16; ++j) aS2s[j] = fmaf(du, wd[sc0 + j], aS2s[j]);
            #pragma unroll
            for (int j = 0; j < 8; ++j)  aS2g[j] = fmaf(du, wd[128 + wv0 + j], aS2g[j]);
        }
    }

    // ---------------- epilogue: all in registers, direct stores
    const float x2s = x2r.x;
    float* orow = out + e * 320;
    #pragma unroll
    for (int q = 0; q < 4; ++q) {
        float o[4];
        #pragma unroll
        for (int r = 0; r < 4; ++r) {
            const int j = q * 4 + r;
            float s = fmaf(aS1s[j], x2s, aS2s[j]);
            o[r] = s * sigmoidf_(s) * aWs[j];
        }
        *(float4*)(orow + sc0 + q * 4) = make_float4(o[0], o[1], o[2], o[3]);
    }
    float x2v[3] = {x2r.y, x2r.z, x2r.w};
    float vo[24];
    #pragma unroll
    for (int j = 0; j < 8; ++j) {
        float g  = fmaf(aS1g[j], x2s, aS2g[j]);
        float sg = sigmoidf_(g) * aWg[j];
        #pragma unroll
        for (int i = 0; i < 3; ++i)
            vo[j*3 + i] = sg * fmaf(aS1v[j], x2v[i], aA3[j][i] * x2s);
    }
    #pragma unroll
    for (int q = 0; q < 6; ++q)
        *(float4*)(orow + 128 + wv0 * 3 + q * 4) =
            make_float4(vo[q*4], vo[q*4+1], vo[q*4+2], vo[q*4+3]);
}

// ---------------------------------------------------------------- launch
extern "C" void kernel_launch(void* const* d_in, const int* in_sizes, int n_in,
                              void* d_out, int out_size, void* d_ws, size_t ws_size,
                              hipStream_t stream) {
    const float* fea_in1 = (const float*)d_in[0];
    const float* fea_in2 = (const float*)d_in[1];
    const float* fea_w   = (const float*)d_in[2];
    // d_in[3] = batch_edge (unused by reference)
    const float* w1_p0 = (const float*)d_in[4];
    const float* w2_p0 = (const float*)d_in[5];
    const float* w1_p1 = (const float*)d_in[6];
    const float* w2_p1 = (const float*)d_in[7];
    const float* w1_p2 = (const float*)d_in[8];
    const float* w2_p2 = (const float*)d_in[9];
    const float* w1_p3 = (const float*)d_in[10];
    const float* w2_p3 = (const float*)d_in[11];
    const float* w1_p4 = (const float*)d_in[12];
    const float* w2_p4 = (const float*)d_in[13];
    const float* w1_p5 = (const float*)d_in[14];
    const float* w2_p5 = (const float*)d_in[15];
    const float* fc_w0 = (const float*)d_in[16];
    const float* fc_b0 = (const float*)d_in[17];
    const float* fc_w1 = (const float*)d_in[18];
    const float* fc_b1 = (const float*)d_in[19];
    const float* fc_w2 = (const float*)d_in[20];
    const float* fc_b2 = (const float*)d_in[21];

    const int E = in_sizes[0] / 320;   // 200000

    float* ws   = (float*)d_ws;
    float* Wbig = ws;                  // 32768 floats
    float* Wd   = ws + 32768;          // 12288 floats
    float* Wp3  = ws + 45056;          // 4096 floats
    float* out  = (float*)d_out;

    prep_weights<<<192, 256, 0, stream>>>(w1_p0, w2_p0, w1_p1, w2_p1, w1_p2, w2_p2,
                                          w1_p3, w2_p3, w1_p4, w2_p4, w1_p5, w2_p5,
                                          Wbig, Wd, Wp3);
    fused_kernel<<<E/64, 512, 0, stream>>>(fea_in1, fea_in2, fea_w,
                                           fc_w0, fc_b0, fc_w1, fc_b1, fc_w2, fc_b2,
                                           Wbig, Wd, Wp3, out);
}

// Round 2
// 1119.587 us; speedup vs baseline: 1.2398x; 1.1372x over previous
//
#include <hip/hip_runtime.h>

// EquiConv fully-fused pipeline (round 3).
// E = 200000, MUL_S = 128, MUL_V = 64, FC_IN = 128, FC_HID = 64, LEN_W = 192.
//
// lane = edge (64 lanes = 64 edges/block), wave = column slice; 8 waves/block.
// Weights stream through SGPRs (wave-uniform addresses). Activations are now
// staged through LDS with COALESCED global loads (round-2's per-lane row loads
// were 64-line-divergent and latency-bound), read back with conflict-free
// odd-pitch ds_read_b32. LDS regions are phase-aliased to fit 48.25 KB:
//   phase S1 : S = [64][129] x1s tile (8256 f)  | H unused
//   phase FC : S = [64][129] fea_w tile, then h1 [64cols][64] in S[0,4096)
//              H = h0 [64cols][64] (4096 f)
//   phase vec: whole lds = [64][193] x1v tile (12352 f)
// fea_w / x1v tiles are prefetched into registers one phase early (T14 split).
//
// ws layout (floats):
//   [0)      Wbig 128x256 = [w1_p0|w1_p1|w1_p2] cols pre-scaled (w2_*, INV_S, SQ2)
//   [32768)  Wd   64x192  = [w1_p4|w1_p5] cols pre-scaled (w2_*, INV_V, SQ3, SQ2)
//   [45056)  Wp3  64x64   = w1_p3 cols pre-scaled (w2_p3, INV_V, SQ2)

__device__ __forceinline__ float sigmoidf_(float x) { return 1.0f / (1.0f + __expf(-x)); }

// ---------------------------------------------------------------- prep
__global__ __launch_bounds__(256) void prep_weights(
    const float* __restrict__ w1_p0, const float* __restrict__ w2_p0,
    const float* __restrict__ w1_p1, const float* __restrict__ w2_p1,
    const float* __restrict__ w1_p2, const float* __restrict__ w2_p2,
    const float* __restrict__ w1_p3, const float* __restrict__ w2_p3,
    const float* __restrict__ w1_p4, const float* __restrict__ w2_p4,
    const float* __restrict__ w1_p5, const float* __restrict__ w2_p5,
    float* __restrict__ Wbig, float* __restrict__ Wd, float* __restrict__ Wp3)
{
    const float INV_S = 0.08838834764831845f;   // 1/sqrt(128)
    const float INV_V = 0.125f;                 // 1/sqrt(64)
    const float SQ2   = 0.7071067811865476f;
    const float SQ3   = 0.5773502691896258f;
    int gid = blockIdx.x * 256 + threadIdx.x;
    if (gid < 128*256) {
        int k = gid >> 8, c = gid & 255;
        float v;
        if (c < 128)      v = w1_p0[k*128 + c]       * w2_p0[c]       * (INV_S*SQ2);
        else if (c < 192) v = w1_p1[k*64 + (c-128)]  * w2_p1[c-128]   * (INV_S*SQ2);
        else              v = w1_p2[k*64 + (c-192)]  * w2_p2[c-192]   * (INV_S*SQ2);
        Wbig[gid] = v;
    } else if (gid < 128*256 + 64*192) {
        int g = gid - 128*256;
        int u = g / 192, c = g - u*192;
        float v;
        if (c < 128) v = w1_p4[u*128 + c]        * w2_p4[c]     * (INV_V*SQ3*SQ2);
        else         v = w1_p5[u*64 + (c-128)]   * w2_p5[c-128] * (INV_V*SQ3*SQ2);
        Wd[g] = v;
    } else if (gid < 128*256 + 64*192 + 64*64) {
        int g = gid - (128*256 + 64*192);
        int w = g & 63;
        Wp3[g] = w1_p3[g] * w2_p3[w] * (INV_V*SQ2);
    }
}

// ---------------------------------------------------------------- fused
__global__ __launch_bounds__(512) void fused_kernel(
    const float* __restrict__ fea_in1, const float* __restrict__ fea_in2,
    const float* __restrict__ fea_w,
    const float* __restrict__ fc_w0, const float* __restrict__ fc_b0,
    const float* __restrict__ fc_w1, const float* __restrict__ fc_b1,
    const float* __restrict__ fc_w2, const float* __restrict__ fc_b2,
    const float* __restrict__ Wbig, const float* __restrict__ Wd,
    const float* __restrict__ Wp3,
    float* __restrict__ out)
{
    __shared__ float lds[12352];          // 49408 B
    float* S = lds;                       // [64][129] pitch-129 tile (8256 floats)
    float* H = lds + 8256;                // h0 [64 cols][64 edges] (4096 floats)

    const int t   = threadIdx.x;
    const int l   = t & 63;                                  // lane = edge-in-block
    const int wid = __builtin_amdgcn_readfirstlane(t >> 6);  // uniform wave id 0..7
    const int sc0 = wid * 16;    // this wave's scal-column base (0..112)
    const int wv0 = wid * 8;     // this wave's w-index base     (0..56)
    const long e0b = (long)blockIdx.x * 64;
    const long e   = e0b + l;

    // ---- stage x1s tile (coalesced) -> S[e][k], pitch 129
    #pragma unroll
    for (int r = 0; r < 4; ++r) {
        int f = t + r*512;                // 2048 float4 = 64x128
        int ee = f >> 5, c4 = f & 31;
        float4 v = *(const float4*)(fea_in1 + (e0b + ee)*320 + c4*4);
        float* d = &S[ee*129 + c4*4];
        d[0] = v.x; d[1] = v.y; d[2] = v.z; d[3] = v.w;
    }
    // ---- prefetch fea_w tile into regs (coalesced; written to LDS after S1)
    float4 fwst[4];
    #pragma unroll
    for (int r = 0; r < 4; ++r) {
        int f = t + r*512;
        int ee = f >> 5, c4 = f & 31;
        fwst[r] = *(const float4*)(fea_w + (e0b + ee)*128 + c4*4);
    }
    float4 x2r = *(const float4*)(fea_in2 + e*4);   // contiguous per lane: coalesced
    __syncthreads();

    // ---------------- S1 = x1s @ Wbig; 16 scal + 8 gate + 8 vcoef cols, K=128
    float aS1s[16], aS1g[8], aS1v[8];
    #pragma unroll
    for (int j = 0; j < 16; ++j) aS1s[j] = 0.f;
    #pragma unroll
    for (int j = 0; j < 8; ++j) { aS1g[j] = 0.f; aS1v[j] = 0.f; }
    #pragma unroll 2
    for (int k = 0; k < 128; ++k) {
        float x = S[l*129 + k];                    // bank (l+k)%32: conflict-free
        const float* wr = Wbig + k*256;            // uniform -> s_load
        #pragma unroll
        for (int j = 0; j < 16; ++j) aS1s[j] = fmaf(x, wr[sc0 + j], aS1s[j]);
        #pragma unroll
        for (int j = 0; j < 8; ++j)  aS1g[j] = fmaf(x, wr[128 + wv0 + j], aS1g[j]);
        #pragma unroll
        for (int j = 0; j < 8; ++j)  aS1v[j] = fmaf(x, wr[192 + wv0 + j], aS1v[j]);
    }
    __syncthreads();                               // all x1s reads done

    // ---- write fea_w tile into S; prefetch x1v tile into regs
    #pragma unroll
    for (int r = 0; r < 4; ++r) {
        int f = t + r*512;
        int ee = f >> 5, c4 = f & 31;
        float* d = &S[ee*129 + c4*4];
        d[0] = fwst[r].x; d[1] = fwst[r].y; d[2] = fwst[r].z; d[3] = fwst[r].w;
    }
    float4 xvst[6];
    #pragma unroll
    for (int r = 0; r < 6; ++r) {
        int f = t + r*512;                // 3072 float4 = 64x192
        int ee = f / 48, c4 = f - ee*48;
        xvst[r] = *(const float4*)(fea_in1 + (e0b + ee)*320 + 128 + c4*4);
    }
    __syncthreads();

    // ---------------- FC layer 0: h0 = silu(fw @ w0 + b0); 8 cols, K=128
    float ha[8];
    #pragma unroll
    for (int j = 0; j < 8; ++j) ha[j] = fc_b0[wv0 + j];
    #pragma unroll 4
    for (int k = 0; k < 128; ++k) {
        float x = S[l*129 + k];
        const float* wr = fc_w0 + k*64 + wv0;
        #pragma unroll
        for (int j = 0; j < 8; ++j) ha[j] = fmaf(x, wr[j], ha[j]);
    }
    #pragma unroll
    for (int j = 0; j < 8; ++j) {
        float z = ha[j];
        H[(wv0 + j)*64 + l] = z * sigmoidf_(z);
    }
    __syncthreads();                               // h0 ready; fea_w reads done

    // ---------------- FC layer 1: h1 = silu(h0 @ w1 + b1); 8 cols, K=64
    // reads H, writes h1 into S[0,4096) (fea_w dead) -> disjoint, no mid barrier
    #pragma unroll
    for (int j = 0; j < 8; ++j) ha[j] = fc_b1[wv0 + j];
    #pragma unroll 4
    for (int k = 0; k < 64; ++k) {
        float x = H[k*64 + l];                     // bank l%32: 2-way, free
        const float* wr = fc_w1 + k*64 + wv0;
        #pragma unroll
        for (int j = 0; j < 8; ++j) ha[j] = fmaf(x, wr[j], ha[j]);
    }
    #pragma unroll
    for (int j = 0; j < 8; ++j) {
        float z = ha[j];
        S[(wv0 + j)*64 + l] = z * sigmoidf_(z);
    }
    __syncthreads();                               // h1 ready

    // ---------------- FC layer 2: W = h1 @ w2 + b2; 16 scal + 8 gate cols, K=64
    float aWs[16], aWg[8];
    #pragma unroll
    for (int j = 0; j < 16; ++j) aWs[j] = fc_b2[sc0 + j];
    #pragma unroll
    for (int j = 0; j < 8; ++j)  aWg[j] = fc_b2[128 + wv0 + j];
    #pragma unroll 2
    for (int k = 0; k < 64; ++k) {
        float x = S[k*64 + l];
        const float* wr = fc_w2 + k*192;
        #pragma unroll
        for (int j = 0; j < 16; ++j) aWs[j] = fmaf(x, wr[sc0 + j], aWs[j]);
        #pragma unroll
        for (int j = 0; j < 8; ++j)  aWg[j] = fmaf(x, wr[128 + wv0 + j], aWg[j]);
    }
    __syncthreads();                               // h1 reads done before overwrite

    // ---- write x1v tile over the whole LDS: [64][193], pitch 193
    #pragma unroll
    for (int r = 0; r < 6; ++r) {
        int f = t + r*512;
        int ee = f / 48, c4 = f - ee*48;
        float* d = &lds[ee*193 + c4*4];
        d[0] = xvst[r].x; d[1] = xvst[r].y; d[2] = xvst[r].z; d[3] = xvst[r].w;
    }
    __syncthreads();

    // ---------------- vector branch: A3 (8w x 3i), d, S2 (16 scal + 8 gate), K=64
    const float c1 = x2r.y, c2 = x2r.z, c3 = x2r.w;
    float aS2s[16], aS2g[8], aA3[8][3];
    #pragma unroll
    for (int j = 0; j < 16; ++j) aS2s[j] = 0.f;
    #pragma unroll
    for (int j = 0; j < 8; ++j) {
        aS2g[j] = 0.f;
        aA3[j][0] = 0.f; aA3[j][1] = 0.f; aA3[j][2] = 0.f;
    }
    #pragma unroll 2
    for (int u = 0; u < 64; ++u) {
        float v0 = lds[l*193 + u*3 + 0];           // bank (l+3u+i)%32: conflict-free
        float v1 = lds[l*193 + u*3 + 1];
        float v2 = lds[l*193 + u*3 + 2];
        const float* wp = Wp3 + u*64 + wv0;
        #pragma unroll
        for (int j = 0; j < 8; ++j) {
            const float w = wp[j];
            aA3[j][0] = fmaf(v0, w, aA3[j][0]);
            aA3[j][1] = fmaf(v1, w, aA3[j][1]);
            aA3[j][2] = fmaf(v2, w, aA3[j][2]);
        }
        const float du = v0*c1 + v1*c2 + v2*c3;
        const float* wd = Wd + u*192;
        #pragma unroll
        for (int j = 0; j < 16; ++j) aS2s[j] = fmaf(du, wd[sc0 + j], aS2s[j]);
        #pragma unroll
        for (int j = 0; j < 8; ++j)  aS2g[j] = fmaf(du, wd[128 + wv0 + j], aS2g[j]);
    }

    // ---------------- epilogue: all in registers, direct stores
    const float x2s = x2r.x;
    float* orow = out + e*320;
    #pragma unroll
    for (int q = 0; q < 4; ++q) {
        float o[4];
        #pragma unroll
        for (int r = 0; r < 4; ++r) {
            const int j = q*4 + r;
            float s = fmaf(aS1s[j], x2s, aS2s[j]);
            o[r] = s * sigmoidf_(s) * aWs[j];
        }
        *(float4*)(orow + sc0 + q*4) = make_float4(o[0], o[1], o[2], o[3]);
    }
    float x2v[3] = {c1, c2, c3};
    float vo[24];
    #pragma unroll
    for (int j = 0; j < 8; ++j) {
        float g  = fmaf(aS1g[j], x2s, aS2g[j]);
        float sg = sigmoidf_(g) * aWg[j];
        #pragma unroll
        for (int i = 0; i < 3; ++i)
            vo[j*3 + i] = sg * fmaf(aS1v[j], x2v[i], aA3[j][i] * x2s);
    }
    #pragma unroll
    for (int q = 0; q < 6; ++q)
        *(float4*)(orow + 128 + wv0*3 + q*4) =
            make_float4(vo[q*4], vo[q*4+1], vo[q*4+2], vo[q*4+3]);
}

// ---------------------------------------------------------------- launch
extern "C" void kernel_launch(void* const* d_in, const int* in_sizes, int n_in,
                              void* d_out, int out_size, void* d_ws, size_t ws_size,
                              hipStream_t stream) {
    const float* fea_in1 = (const float*)d_in[0];
    const float* fea_in2 = (const float*)d_in[1];
    const float* fea_w   = (const float*)d_in[2];
    // d_in[3] = batch_edge (unused by reference)
    const float* w1_p0 = (const float*)d_in[4];
    const float* w2_p0 = (const float*)d_in[5];
    const float* w1_p1 = (const float*)d_in[6];
    const float* w2_p1 = (const float*)d_in[7];
    const float* w1_p2 = (const float*)d_in[8];
    const float* w2_p2 = (const float*)d_in[9];
    const float* w1_p3 = (const float*)d_in[10];
    const float* w2_p3 = (const float*)d_in[11];
    const float* w1_p4 = (const float*)d_in[12];
    const float* w2_p4 = (const float*)d_in[13];
    const float* w1_p5 = (const float*)d_in[14];
    const float* w2_p5 = (const float*)d_in[15];
    const float* fc_w0 = (const float*)d_in[16];
    const float* fc_b0 = (const float*)d_in[17];
    const float* fc_w1 = (const float*)d_in[18];
    const float* fc_b1 = (const float*)d_in[19];
    const float* fc_w2 = (const float*)d_in[20];
    const float* fc_b2 = (const float*)d_in[21];

    const int E = in_sizes[0] / 320;   // 200000

    float* ws   = (float*)d_ws;
    float* Wbig = ws;                  // 32768 floats
    float* Wd   = ws + 32768;          // 12288 floats
    float* Wp3  = ws + 45056;          // 4096 floats
    float* out  = (float*)d_out;

    prep_weights<<<192, 256, 0, stream>>>(w1_p0, w2_p0, w1_p1, w2_p1, w1_p2, w2_p2,
                                          w1_p3, w2_p3, w1_p4, w2_p4, w1_p5, w2_p5,
                                          Wbig, Wd, Wp3);
    fused_kernel<<<E/64, 512, 0, stream>>>(fea_in1, fea_in2, fea_w,
                                           fc_w0, fc_b0, fc_w1, fc_b1, fc_w2, fc_b2,
                                           Wbig, Wd, Wp3, out);
}